// Round 10
// baseline (25007.248 us; speedup 1.0000x reference)
//
#include <hip/hip_runtime.h>
#include <hip/hip_bf16.h>

// Problem constants (match the reference)
constexpr int B = 4;
constexpr int N = 16384;
constexpr int S = 4096;       // N * 0.25
constexpr int K = 32;
constexpr float BIG = 1e30f;

// Output layout (flat f32, concatenated in reference return order)
constexpr size_t OFF_COORD = 0;                       // node_coord_dst [B*S*3]
constexpr size_t OFF_ESRC  = (size_t)B * S * 3;       // edge_src [B*S*K]
constexpr size_t OFF_EDST  = OFF_ESRC + (size_t)B * S * K;
constexpr size_t OFF_MASK  = OFF_EDST + (size_t)B * S * K;
constexpr size_t OFF_DEG   = OFF_MASK + (size_t)B * S * K;
constexpr size_t OFF_BATCH = OFF_DEG + (size_t)B * S;
constexpr size_t OFF_NIDX  = OFF_BATCH + (size_t)B * S;

// ============ Kernel 0: Morton counting-sort (one block per cloud) =========
#define NT_MS 1024
__global__ __launch_bounds__(NT_MS)
void morton_sort_kernel(const float* __restrict__ pts, float4* __restrict__ sbuf) {
    const int b = blockIdx.x, t = threadIdx.x;
    const int lane = t & 63, wave = t >> 6;
    const float* p = pts + (size_t)b * N * 3;
    float4* sb = sbuf + (size_t)b * N;

    __shared__ unsigned int cnt[8192];   // 16384 u16 counters packed
    __shared__ int s_wsum[16];

    for (int i = t; i < 8192; i += NT_MS) cnt[i] = 0u;
    __syncthreads();

    float xx[16], yy[16], zz[16];
    int code[16];
#pragma unroll
    for (int j = 0; j < 16; ++j) {
        int i = t + j * NT_MS;
        float x = p[i * 3 + 0], y = p[i * 3 + 1], z = p[i * 3 + 2];
        xx[j] = x; yy[j] = y; zz[j] = z;
        int xi = min(31, (int)(x * 32.0f));
        int yi = min(31, (int)(y * 32.0f));
        int zi = min(15, (int)(z * 16.0f));
        int c = 0;
#pragma unroll
        for (int k = 0; k < 4; ++k) {
            c |= ((zi >> k) & 1) << (3 * k);
            c |= ((yi >> k) & 1) << (3 * k + 1);
            c |= ((xi >> k) & 1) << (3 * k + 2);
        }
        c |= ((xi >> 4) & 1) << 12;
        c |= ((yi >> 4) & 1) << 13;
        code[j] = c;
        atomicAdd(&cnt[c >> 1], (c & 1) ? 0x10000u : 1u);
    }
    __syncthreads();

    unsigned int w[8];
    int tot = 0;
#pragma unroll
    for (int k = 0; k < 8; ++k) {
        w[k] = cnt[t * 8 + k];
        tot += (int)(w[k] & 0xffffu) + (int)(w[k] >> 16);
    }
    int inc = tot;
#pragma unroll
    for (int off = 1; off < 64; off <<= 1) {
        int v = __shfl_up(inc, off);
        if (lane >= off) inc += v;
    }
    if (lane == 63) s_wsum[wave] = inc;
    __syncthreads();
    int wbase = 0;
#pragma unroll
    for (int q = 0; q < 16; ++q) {
        int v = s_wsum[q];
        if (q < wave) wbase += v;
    }
    int excl = wbase + inc - tot;
#pragma unroll
    for (int k = 0; k < 8; ++k) {
        unsigned int c0 = (unsigned int)excl;
        unsigned int c1 = c0 + (w[k] & 0xffffu);
        cnt[t * 8 + k] = c0 | (c1 << 16);
        excl = (int)(c1 + (w[k] >> 16));
    }
    __syncthreads();

#pragma unroll
    for (int j = 0; j < 16; ++j) {
        int i = t + j * NT_MS;
        int c = code[j];
        unsigned int old = atomicAdd(&cnt[c >> 1], (c & 1) ? 0x10000u : 1u);
        int pos = (c & 1) ? (int)(old >> 16) : (int)(old & 0xffffu);
        sb[pos] = make_float4(xx[j], yy[j], zz[j], __int_as_float(i));
    }
}

// ============ Kernel 1: candidate-list FPS (one block per cloud) ============
// Exact FPS. Keys (dd_bits<<32 | ~orig) live in LDS s_key[N]; chunk (=thread)
// keeps only bbox + chunk-max key in regs (~50 VGPR, under the allocator's
// 64-VGPR grant at 1024 thr -> no spills). Wave 0 runs "cheap" steps entirely
// in registers from a compacted candidate list (all points with dd > theta);
// the guard (list max > theta_key) makes each cheap winner provably the true
// argmax. Rebuild: batch-apply pending centers (bbox-pruned; skipped centers
// are provably no-ops so cached values stay exact), block argmax = that
// step's winner, pick theta by 4-candidate count ladder, compact list.
#define NT_FP 1024
#define CPT 16
#define LISTCAP 128
#define PENDCAP 64          // pending-center hotmask fits one u64
#define BOOT 64             // steps before first list build

__global__ __launch_bounds__(NT_FP, 1)
void fps_pruned_kernel(const float* __restrict__ pts, const float4* __restrict__ sbuf,
                       int* __restrict__ seq) {
    const int b = blockIdx.x, t = threadIdx.x;
    const int lane = t & 63, wave = t >> 6;
    const float4* sb = sbuf + (size_t)b * N;

    __shared__ unsigned long long s_key[N];          // 128 KB
    __shared__ unsigned long long s_lkey[LISTCAP];
    __shared__ float s_lx[LISTCAP], s_ly[LISTCAP], s_lz[LISTCAP];
    __shared__ int   s_lslot[LISTCAP];
    __shared__ float s_px[PENDCAP], s_py[PENDCAP], s_pz[PENDCAP];
    __shared__ unsigned int s_dirty[NT_FP / 32];
    __shared__ unsigned long long s_red;
    __shared__ int s_cnt[4];
    __shared__ int s_listcnt;
    __shared__ int s_npend;
    __shared__ int s_step;
    __shared__ float s_wx, s_wy, s_wz;
    __shared__ unsigned long long s_theta;

    float bx0 = BIG, by0 = BIG, bz0 = BIG, bx1 = -BIG, by1 = -BIG, bz1 = -BIG;
#pragma unroll
    for (int j = 0; j < CPT; ++j) {
        float4 v = sb[t * CPT + j];
        s_key[t * CPT + j] =
            ((unsigned long long)__float_as_uint(BIG) << 32) |
            (~(unsigned int)__float_as_int(v.w));
        bx0 = fminf(bx0, v.x); bx1 = fmaxf(bx1, v.x);
        by0 = fminf(by0, v.y); by1 = fmaxf(by1, v.y);
        bz0 = fminf(bz0, v.z); bz1 = fmaxf(bz1, v.z);
    }
    unsigned long long bkey =
        ((unsigned long long)__float_as_uint(BIG) << 32) | 0xFFFFFFFFull;
    int bj = 0;     // chunk-argmax j; valid whenever bkey recomputed (rebuild 1
                    // makes every chunk hot, so the init value is never reduced)

    if (t == 0) {
        const float* p = pts + (size_t)b * N * 3;
        seq[b * S + 0] = 0;                  // random_start=False
        s_px[0] = p[0]; s_py[0] = p[1]; s_pz[0] = p[2];
        s_npend = 1; s_step = 1;
        s_theta = ~0ull;                     // guard always fails -> rebuild
        s_listcnt = 0; s_red = 0ull;
    }
    if (t < NT_FP / 32) s_dirty[t] = 0u;
    if (t < 4) s_cnt[t] = 0;
    __syncthreads();

    for (;;) {
        // -------- cheap phase: wave 0 only (others wait at the barrier) -----
        if (wave == 0) {
            const int lc = s_listcnt;
            const unsigned long long th = s_theta;
            unsigned long long k0 = 0ull, k1 = 0ull;
            float ex0 = 0.f, ey0 = 0.f, ez0 = 0.f;
            float ex1 = 0.f, ey1 = 0.f, ez1 = 0.f;
            int sl0 = 0, sl1 = 0;
            if (lane < lc) {
                k0 = s_lkey[lane]; ex0 = s_lx[lane];
                ey0 = s_ly[lane];  ez0 = s_lz[lane]; sl0 = s_lslot[lane];
            }
            if (lane + 64 < lc) {
                k1 = s_lkey[lane + 64]; ex1 = s_lx[lane + 64];
                ey1 = s_ly[lane + 64];  ez1 = s_lz[lane + 64];
                sl1 = s_lslot[lane + 64];
            }
            int np = s_npend;
            int st = s_step;
            float cx = s_px[np - 1], cy = s_py[np - 1], cz = s_pz[np - 1];
            while (st < S && np < PENDCAP) {
                {   // exact update of entry 0 vs newest center
                    float dx = __fsub_rn(ex0, cx), dy = __fsub_rn(ey0, cy),
                          dz = __fsub_rn(ez0, cz);
                    float d = __fadd_rn(__fadd_rn(__fmul_rn(dx, dx),
                              __fmul_rn(dy, dy)), __fmul_rn(dz, dz));
                    float v = __uint_as_float((unsigned int)(k0 >> 32));
                    float nv = fminf(v, d);
                    k0 = ((unsigned long long)__float_as_uint(nv) << 32) |
                         (unsigned int)k0;
                }
                {   // entry 1
                    float dx = __fsub_rn(ex1, cx), dy = __fsub_rn(ey1, cy),
                          dz = __fsub_rn(ez1, cz);
                    float d = __fadd_rn(__fadd_rn(__fmul_rn(dx, dx),
                              __fmul_rn(dy, dy)), __fmul_rn(dz, dz));
                    float v = __uint_as_float((unsigned int)(k1 >> 32));
                    float nv = fminf(v, d);
                    k1 = ((unsigned long long)__float_as_uint(nv) << 32) |
                         (unsigned int)k1;
                }
                unsigned long long mk = (k0 > k1) ? k0 : k1;
                unsigned long long r = mk;
#pragma unroll
                for (int off = 32; off >= 1; off >>= 1) {
                    unsigned long long o = __shfl_xor(r, off);
                    r = (o > r) ? o : r;
                }
                if (r <= th) break;            // winner might be off-list
                unsigned long long mask = __ballot(mk == r);   // keys unique
                int wl = (int)__builtin_ctzll(mask);
                int sel = (k1 == r) ? 1 : 0;                   // on lane wl
                float wx = __shfl(sel ? ex1 : ex0, wl);
                float wy = __shfl(sel ? ey1 : ey0, wl);
                float wz = __shfl(sel ? ez1 : ez0, wl);
                int   ws = __shfl(sel ? sl1 : sl0, wl);
                if (lane == wl) { if (sel) k1 = 0ull; else k0 = 0ull; }
                if (lane == 0) {
                    seq[b * S + st] = (int)(~(unsigned int)r);
                    s_key[ws] = 0ull;          // consumed: dd -> 0 (exact)
                    atomicOr(&s_dirty[(ws >> 4) >> 5], 1u << ((ws >> 4) & 31));
                    s_px[np] = wx; s_py[np] = wy; s_pz[np] = wz;
                }
                cx = wx; cy = wy; cz = wz;
                ++np; ++st;
            }
            if (lane == 0) { s_step = st; s_npend = np; }
        }
        __syncthreads();                                       // B0
        const int step = s_step;
        if (step >= S) break;
        const int np = s_npend;

        // -------- rebuild: batch-apply pending centers (bbox-pruned) -------
        if (t == 0) s_listcnt = 0;
        if (t < 4) s_cnt[t] = 0;
        {
            unsigned long long hot = 0ull;
            const float bmax0 = __uint_as_float((unsigned int)(bkey >> 32));
            for (int c = 0; c < np; ++c) {
                float cx = s_px[c], cy = s_py[c], cz = s_pz[c];
                float tx = fmaxf(fmaxf(bx0 - cx, cx - bx1), 0.0f);
                float ty = fmaxf(fmaxf(by0 - cy, cy - by1), 0.0f);
                float tz = fmaxf(fmaxf(bz0 - cz, cz - bz1), 0.0f);
                float lb = tx * tx + ty * ty + tz * tz;
                if (lb * 0.999998f < bmax0) hot |= (1ull << c);
            }
            bool dirty = (s_dirty[t >> 5] >> (t & 31)) & 1u;
            if (hot) {
                unsigned long long m = 0ull; int mj = 0;
#pragma unroll
                for (int j = 0; j < CPT; ++j) {
                    int slot = t * CPT + j;
                    float4 v = sb[slot];                // L2-resident
                    unsigned long long k = s_key[slot];
                    float val = __uint_as_float((unsigned int)(k >> 32));
                    unsigned long long hh = hot;
                    while (hh) {
                        int c = (int)__builtin_ctzll(hh); hh &= hh - 1;
                        float dx = __fsub_rn(v.x, s_px[c]);
                        float dy = __fsub_rn(v.y, s_py[c]);
                        float dz = __fsub_rn(v.z, s_pz[c]);
                        float d = __fadd_rn(__fadd_rn(__fmul_rn(dx, dx),
                                  __fmul_rn(dy, dy)), __fmul_rn(dz, dz));
                        val = fminf(val, d);            // exact running min
                    }
                    k = ((unsigned long long)__float_as_uint(val) << 32) |
                        (unsigned int)k;
                    s_key[slot] = k;
                    if (k > m) { m = k; mj = j; }
                }
                bkey = m; bj = mj;
            } else if (dirty) {                         // consumed point here
                unsigned long long m = 0ull; int mj = 0;
#pragma unroll
                for (int j = 0; j < CPT; ++j) {
                    unsigned long long k = s_key[t * CPT + j];
                    if (k > m) { m = k; mj = j; }
                }
                bkey = m; bj = mj;
            }
            // block argmax of exact per-chunk maxima
            unsigned long long r = bkey;
#pragma unroll
            for (int off = 32; off >= 1; off >>= 1) {
                unsigned long long o = __shfl_xor(r, off);
                r = (o > r) ? o : r;
            }
            if (lane == 0) atomicMax((unsigned long long*)&s_red, r);
        }
        __syncthreads();                                       // B1
        const unsigned long long g = s_red;
        if (bkey == g) {                    // unique owner (keys unique)
            int wslot = t * CPT + bj;
            float4 v = sb[wslot];
            seq[b * S + step] = (int)(~(unsigned int)g);
            s_wx = v.x; s_wy = v.y; s_wz = v.z;
            s_key[wslot] = 0ull;            // consumed
            unsigned long long m = 0ull; int mj = 0;
#pragma unroll
            for (int j = 0; j < CPT; ++j) {
                unsigned long long k = s_key[t * CPT + j];
                if (k > m) { m = k; mj = j; }
            }
            bkey = m; bj = mj;
        }
        if (t < NT_FP / 32) s_dirty[t] = 0u;
        {
            // counts vs 4 theta candidates (own chunk only -> no races)
            float vmax = __uint_as_float((unsigned int)(g >> 32));
            unsigned long long tk0 =
                ((unsigned long long)__float_as_uint(vmax * 0.45f) << 32) | 0xFFFFFFFFull;
            unsigned long long tk1 =
                ((unsigned long long)__float_as_uint(vmax * 0.65f) << 32) | 0xFFFFFFFFull;
            unsigned long long tk2 =
                ((unsigned long long)__float_as_uint(vmax * 0.82f) << 32) | 0xFFFFFFFFull;
            unsigned long long tk3 =
                ((unsigned long long)__float_as_uint(vmax * 0.93f) << 32) | 0xFFFFFFFFull;
            int c0 = 0, c1 = 0, c2 = 0, c3 = 0;
#pragma unroll
            for (int j = 0; j < CPT; ++j) {
                unsigned long long k = s_key[t * CPT + j];
                c0 += (k > tk0); c1 += (k > tk1); c2 += (k > tk2); c3 += (k > tk3);
            }
#pragma unroll
            for (int off = 32; off >= 1; off >>= 1) {
                c0 += __shfl_xor(c0, off); c1 += __shfl_xor(c1, off);
                c2 += __shfl_xor(c2, off); c3 += __shfl_xor(c3, off);
            }
            if (lane == 0) {
                atomicAdd(&s_cnt[0], c0); atomicAdd(&s_cnt[1], c1);
                atomicAdd(&s_cnt[2], c2); atomicAdd(&s_cnt[3], c3);
            }
        }
        __syncthreads();                                       // B2
        {
            float vmax = __uint_as_float((unsigned int)(g >> 32));
            int n0 = s_cnt[0], n1 = s_cnt[1], n2 = s_cnt[2], n3 = s_cnt[3];
            float f = -1.0f;
            if      (n0 > 0 && n0 <= LISTCAP) f = 0.45f;
            else if (n1 > 0 && n1 <= LISTCAP) f = 0.65f;
            else if (n2 > 0 && n2 <= LISTCAP) f = 0.82f;
            else if (n3 > 0 && n3 <= LISTCAP) f = 0.93f;
            bool dolist = (f > 0.0f) && (step >= BOOT);
            unsigned long long thk = dolist
                ? (((unsigned long long)__float_as_uint(vmax * f) << 32) |
                   0xFFFFFFFFull)
                : ~0ull;
            if (t == 0) {
                s_theta = thk; s_red = 0ull; s_step = step + 1;
                s_npend = 1; s_px[0] = s_wx; s_py[0] = s_wy; s_pz[0] = s_wz;
            }
            if (dolist) {
#pragma unroll
                for (int j = 0; j < CPT; ++j) {
                    int slot = t * CPT + j;
                    unsigned long long k = s_key[slot];
                    if (k > thk) {
                        int pos = atomicAdd(&s_listcnt, 1);
                        if (pos < LISTCAP) {
                            float4 v = sb[slot];
                            s_lkey[pos] = k; s_lx[pos] = v.x;
                            s_ly[pos] = v.y; s_lz[pos] = v.z;
                            s_lslot[pos] = slot;
                        }
                    }
                }
            }
        }
        __syncthreads();                                       // B3
    }
}

// ============ Fallback FPS (used only if ws too small) ======================
#define NT_FPS 512
#define PPT (N / NT_FPS)
#define NWAVE (NT_FPS / 64)
__global__ __launch_bounds__(NT_FPS)
void fps_kernel(const float* __restrict__ pts, int* __restrict__ seq) {
    const int b = blockIdx.x;
    const float* p = pts + (size_t)b * N * 3;
    const int t = threadIdx.x;
    const int lane = t & 63;
    const int wave = t >> 6;
    float px[PPT], py[PPT], pz[PPT], dd[PPT];
    const int base = t * PPT;
#pragma unroll
    for (int j = 0; j < PPT; ++j) {
        px[j] = p[(base + j) * 3 + 0];
        py[j] = p[(base + j) * 3 + 1];
        pz[j] = p[(base + j) * 3 + 2];
        dd[j] = BIG;
    }
#pragma unroll
    for (int j = 0; j < PPT; ++j)
        asm volatile("" : "+v"(px[j]), "+v"(py[j]), "+v"(pz[j]));
    __shared__ unsigned long long s_part[2][NWAVE];
    if (t == 0) seq[b * S + 0] = 0;
    float lx = p[0], ly = p[1], lz = p[2];
    for (int step = 1; step < S; ++step) {
        float bv = -1.0f;
        int bi = 0;
#pragma unroll
        for (int j = 0; j < PPT; ++j) {
            float dx = __fsub_rn(px[j], lx);
            float dy = __fsub_rn(py[j], ly);
            float dz = __fsub_rn(pz[j], lz);
            float d  = __fadd_rn(__fadd_rn(__fmul_rn(dx, dx), __fmul_rn(dy, dy)),
                                 __fmul_rn(dz, dz));
            float nd = fminf(dd[j], d);
            dd[j] = nd;
            if (nd > bv) { bv = nd; bi = base + j; }
        }
        unsigned long long key =
            ((unsigned long long)__float_as_uint(bv) << 32) | (unsigned int)(~bi);
#pragma unroll
        for (int off = 32; off >= 1; off >>= 1) {
            unsigned long long o = __shfl_down(key, off);
            if (o > key) key = o;
        }
        if (lane == 0) s_part[step & 1][wave] = key;
        __syncthreads();
        unsigned long long bk = s_part[step & 1][0];
#pragma unroll
        for (int q = 1; q < NWAVE; ++q) {
            unsigned long long o = s_part[step & 1][q];
            if (o > bk) bk = o;
        }
        int wi = (int)(~(unsigned int)bk);
        if (t == 0) seq[b * S + step] = wi;
        int wis = __builtin_amdgcn_readfirstlane(wi);
        lx = p[wis * 3 + 0];
        ly = p[wis * 3 + 1];
        lz = p[wis * 3 + 2];
    }
}

// ============ Kernel 2: sort FPS indices (bitmap rank), gather dst ==========
#define NT_SORT 512
__global__ __launch_bounds__(NT_SORT)
void sort_gather_kernel(const float* __restrict__ pts, const int* __restrict__ seq,
                        int* __restrict__ sorted, float* __restrict__ out) {
    const int b = blockIdx.x;
    const int t = threadIdx.x;
    __shared__ unsigned int bm[N / 32];
    __shared__ int pfx[N / 32];
    __shared__ int s_sorted[S];

    for (int i = t; i < N / 32; i += NT_SORT) bm[i] = 0u;
    __syncthreads();
    for (int i = t; i < S; i += NT_SORT) {
        int v = seq[b * S + i];
        atomicOr(&bm[v >> 5], 1u << (v & 31));
    }
    __syncthreads();

    int myc = __popc(bm[t]);
    pfx[t] = myc;
    __syncthreads();
    for (int off = 1; off < N / 32; off <<= 1) {
        int v = (t >= off) ? pfx[t - off] : 0;
        __syncthreads();
        pfx[t] += v;
        __syncthreads();
    }

    for (int i = t; i < S; i += NT_SORT) {
        int v = seq[b * S + i];
        int w = v >> 5;
        int rank = pfx[w] - __popc(bm[w]) + __popc(bm[w] & ((1u << (v & 31)) - 1u));
        s_sorted[rank] = v;
    }
    __syncthreads();

    for (int r = t; r < S; r += NT_SORT) {
        int v = s_sorted[r];
        int g = b * S + r;
        sorted[g] = v;
        out[OFF_COORD + 3 * (size_t)g + 0] = pts[((size_t)b * N + v) * 3 + 0];
        out[OFF_COORD + 3 * (size_t)g + 1] = pts[((size_t)b * N + v) * 3 + 1];
        out[OFF_COORD + 3 * (size_t)g + 2] = pts[((size_t)b * N + v) * 3 + 2];
        out[OFF_BATCH + g] = (float)b;
        out[OFF_NIDX + g]  = (float)(v + b * N);
    }
}

// ============ Kernel 3: radius ball query, one wave per dst point ===========
#define CAP 512
__global__ __launch_bounds__(256)
void ballq_kernel(const float* __restrict__ pts, const int* __restrict__ sorted,
                  float* __restrict__ out) {
    const int w    = threadIdx.x >> 6;
    const int lane = threadIdx.x & 63;
    const int g    = blockIdx.x * 4 + w;
    const int b    = g >> 12;
    const float R2 = (float)(0.08 * 0.08);

    __shared__ float cd2[4][CAP];
    __shared__ int   cidx[4][CAP];
    __shared__ int   coor[4][K];

    const float Dx = out[OFF_COORD + 3 * (size_t)g + 0];
    const float Dy = out[OFF_COORD + 3 * (size_t)g + 1];
    const float Dz = out[OFF_COORD + 3 * (size_t)g + 2];
    const int self = sorted[g];

    const float* p = pts + (size_t)b * N * 3;
    const unsigned long long ltmask = (lane == 63) ? 0x7fffffffffffffffull
                                                   : ((1ull << lane) - 1ull);
    int cnt = 0, oor = 0;
    for (int i0 = 0; i0 < N; i0 += 64) {
        int i = i0 + lane;
        float dx = __fsub_rn(Dx, p[i * 3 + 0]);
        float dy = __fsub_rn(Dy, p[i * 3 + 1]);
        float dz = __fsub_rn(Dz, p[i * 3 + 2]);
        float d2 = __fadd_rn(__fadd_rn(__fmul_rn(dx, dx), __fmul_rn(dy, dy)),
                             __fmul_rn(dz, dz));
        bool in = (d2 <= R2);
        unsigned long long m = __ballot(in);
        if (in) {
            int pos = cnt + __popcll(m & ltmask);
            if (pos < CAP) { cd2[w][pos] = d2; cidx[w][pos] = i; }
        }
        if (oor < K) {
            unsigned long long m2 = ~m;
            if (!in) {
                int p2 = oor + __popcll(m2 & ltmask);
                if (p2 < K) coor[w][p2] = i;
            }
            oor += __popcll(m2);
            if (oor > K) oor = K;
        }
        cnt += __popcll(m);
    }

    const int M  = cnt < CAP ? cnt : CAP;
    const int Mk = M < K ? M : K;
    const size_t eb = (size_t)g * K;
    int deg = 0;
    for (int c = lane; c < M; c += 64) {
        float myd = cd2[w][c];
        int   myi = cidx[w][c];
        int rank = 0;
        for (int j = 0; j < M; ++j) {
            float dj = cd2[w][j];
            int   ij = cidx[w][j];
            rank += (dj < myd || (dj == myd && ij < myi)) ? 1 : 0;
        }
        if (rank < K) {
            bool valid = (myi != self);
            out[OFF_ESRC + eb + rank] = (float)(myi + b * N);
            out[OFF_MASK + eb + rank] = valid ? 1.0f : 0.0f;
            deg += valid ? 1 : 0;
        }
    }
    for (int r = lane; r < K; r += 64) {
        out[OFF_EDST + eb + r] = (float)g;
        if (r >= Mk) {
            out[OFF_ESRC + eb + r] = (float)(coor[w][r - Mk] + b * N);
            out[OFF_MASK + eb + r] = 0.0f;
        }
    }
#pragma unroll
    for (int off = 32; off >= 1; off >>= 1) deg += __shfl_down(deg, off);
    if (lane == 0) out[OFF_DEG + g] = (float)deg;
}

extern "C" void kernel_launch(void* const* d_in, const int* in_sizes, int n_in,
                              void* d_out, int out_size, void* d_ws, size_t ws_size,
                              hipStream_t stream) {
    const float* pts = (const float*)d_in[0];
    float* out = (float*)d_out;

    const size_t sbuf_bytes = (size_t)B * N * sizeof(float4);   // 1 MB
    const size_t need = sbuf_bytes + 2 * (size_t)B * S * sizeof(int);

    if (ws_size >= need) {
        float4* sbuf = (float4*)d_ws;
        int* seq    = (int*)((char*)d_ws + sbuf_bytes);
        int* sorted = seq + (size_t)B * S;
        morton_sort_kernel<<<B, NT_MS, 0, stream>>>(pts, sbuf);
        fps_pruned_kernel<<<B, NT_FP, 0, stream>>>(pts, sbuf, seq);
        sort_gather_kernel<<<B, NT_SORT, 0, stream>>>(pts, seq, sorted, out);
        ballq_kernel<<<(B * S) / 4, 256, 0, stream>>>(pts, sorted, out);
    } else {
        int* seq    = (int*)d_ws;
        int* sorted = seq + (size_t)B * S;
        fps_kernel<<<B, NT_FPS, 0, stream>>>(pts, seq);
        sort_gather_kernel<<<B, NT_SORT, 0, stream>>>(pts, seq, sorted, out);
        ballq_kernel<<<(B * S) / 4, 256, 0, stream>>>(pts, sorted, out);
    }
}